// Round 10
// baseline (262.822 us; speedup 1.0000x reference)
//
#include <hip/hip_runtime.h>
#include <hip/hip_fp16.h>
#include <math.h>

#define N_NODES   2000000
#define N_MOVABLE 1500000
#define N_FILLER  400000
#define N_NETS    1500000
#define N_PINS    (N_NETS * 4)          // 6,000,000
#define NB        512                   // bins per axis (cropped map)
#define NT        16                    // tiles per axis
#define TILE      32                    // bins per tile axis
#define NBUCKET   (NT * NT)             // 256 tile buckets
#define CAP       10240                 // tile slab capacity per bucket
#define NSLICE    4
#define NMAPS     NSLICE
#define RED_BLOCKS 1024

// --- q-partition (pass 1/2) ---
#define NQ        24                    // q-ranges
#define QRNG      250000                // pins per range (exact: 24*250k = 6M)
#define NXCD      8
#define RPX       3                     // ranges per XCD
#define PIN_PER_XCD (QRNG * RPX)        // 750000
#define P2CHUNK   4096
#define P2CHUNKS  ((PIN_PER_XCD + P2CHUNK - 1) / P2CHUNK)   // 184

__device__ __forceinline__ int bin_idx(float v) {
    // BIN_W = 1000/512 = 1.953125 exactly
    float b = floorf(v / 1.953125f);
    b = fminf(fmaxf(b, 0.0f), 511.0f);
    return (int)b;
}

// ---------------------------------------------------------------------------
// P1: bucket (q, slot) by q-range. Coalesced fnp read, LDS-ranked write.
// ---------------------------------------------------------------------------
__global__ __launch_bounds__(1024)
void p1_bucketq_kernel(const int* __restrict__ fnp,
                       uint2* __restrict__ qslab,
                       unsigned* __restrict__ g_qptr) {
    __shared__ unsigned hist[NQ];
    __shared__ unsigned hbase[NQ];
    int t = threadIdx.x;
    if (t < NQ) hist[t] = 0;
    __syncthreads();

    int s0 = blockIdx.x * 4096 + t * 4;
    unsigned q[4]; unsigned qb[4]; unsigned rk[4]; bool val[4];
    if (s0 + 3 < N_PINS) {
        int4 f = *reinterpret_cast<const int4*>(fnp + s0);
        q[0] = (unsigned)f.x; q[1] = (unsigned)f.y;
        q[2] = (unsigned)f.z; q[3] = (unsigned)f.w;
        val[0] = val[1] = val[2] = val[3] = true;
    } else {
        #pragma unroll
        for (int j = 0; j < 4; ++j) {
            val[j] = (s0 + j < N_PINS);
            q[j] = val[j] ? (unsigned)fnp[s0 + j] : 0u;
        }
    }
    #pragma unroll
    for (int j = 0; j < 4; ++j) {
        qb[j] = q[j] / (unsigned)QRNG;
        rk[j] = val[j] ? atomicAdd(&hist[qb[j]], 1u) : 0u;
    }
    __syncthreads();
    if (t < NQ) {
        unsigned c = hist[t];
        hbase[t] = c ? atomicAdd(&g_qptr[t], c) : 0u;
    }
    __syncthreads();
    #pragma unroll
    for (int j = 0; j < 4; ++j) {
        if (val[j]) {
            unsigned idx = qb[j] * (unsigned)QRNG + hbase[qb[j]] + rk[j];
            qslab[idx] = make_uint2(q[j], (unsigned)(s0 + j));
        }
    }
}

// ---------------------------------------------------------------------------
// P2: XCD-affine gather, direct-slot store. Blocks with bid%8==k cover ranges
// {k, k+8, k+16} (chunk = bid>>3) -> each 2MB pin region is fetched by ONE
// XCD and the gathers L2-hit. Output: sxy[slot] = xq | yq<<16 (plain 4B
// stores; slots are a permutation -> disjoint -> no atomics, no LDS).
// ---------------------------------------------------------------------------
__global__ __launch_bounds__(1024)
void p2_gather_kernel(const uint2* __restrict__ qslab,
                      const float* __restrict__ pin_pos,
                      unsigned* __restrict__ sxy) {
    unsigned k = blockIdx.x & (NXCD - 1);
    unsigned c = blockIdx.x >> 3;
    unsigned t = threadIdx.x;
    #pragma unroll
    for (int j = 0; j < 4; ++j) {
        unsigned s = c * (unsigned)P2CHUNK + t + (unsigned)j * 1024u;
        if (s < (unsigned)PIN_PER_XCD) {
            unsigned rl = s / (unsigned)QRNG;          // 0..2
            unsigned ridx = s - rl * (unsigned)QRNG;
            uint2 qr = qslab[(k + 8u * rl) * (unsigned)QRNG + ridx];
            float x = pin_pos[qr.x];
            float y = pin_pos[qr.x + N_PINS];
            unsigned xq = __float2uint_rn(x * 64.0f);
            unsigned yq = __float2uint_rn(y * 64.0f);
            sxy[qr.y] = xq | (yq << 16);
        }
    }
}

// ---------------------------------------------------------------------------
// Per-net 8-byte tile record (shared):
//   .x = f16x2 {vh, vv};  .y = blx | bly<<9 | spanx<<18 | spany<<23
// ---------------------------------------------------------------------------
__device__ __forceinline__ uint2 pack_tile_rec(float bw, float bh,
                                               unsigned blx, unsigned bhx,
                                               unsigned bly, unsigned bhy,
                                               int* tb) {
    float barea = fmaxf(bw * bh, 1e-6f);
    float vh = fminf((bw / barea) * (1.0f / 1.5f), 60000.0f);
    float vv = fminf((bh / barea) * (1.0f / 1.5f), 60000.0f);
    *tb = (int)((bly >> 5) * NT + (blx >> 5));
    __half2 h = __float22half2_rn(make_float2(vh, vv));
    uint2 r;
    r.x = *reinterpret_cast<unsigned*>(&h);
    r.y = blx | (bly << 9) | ((bhx + 1 - blx) << 18) | ((bhy + 1 - bly) << 23);
    return r;
}

// ---------------------------------------------------------------------------
// P3: net n's pins live at slots 4n..4n+3 -> ONE coalesced uint4 load per net,
// bbox in registers (no LDS reduction), then tile-bucket into slabs.
// Bin math exact: 125 quanta per bin (quantum = 1/64 unit).
// ---------------------------------------------------------------------------
__global__ __launch_bounds__(1024)
void p3_netrec_kernel(const unsigned* __restrict__ sxy,
                      uint2* __restrict__ tslab,
                      unsigned* __restrict__ g_tptr) {
    __shared__ unsigned hist[NBUCKET];
    __shared__ unsigned hbase[NBUCKET];
    int t = threadIdx.x;
    if (t < NBUCKET) hist[t] = 0;
    __syncthreads();

    int n0 = blockIdx.x * 4096 + t;
    uint2 rec[4]; int tb[4]; unsigned rk[4];
    #pragma unroll
    for (int u = 0; u < 4; ++u) {
        int n = n0 + u * 1024;
        tb[u] = -1;
        if (n < N_NETS) {
            uint4 v = *reinterpret_cast<const uint4*>(sxy + 4 * (size_t)n);
            unsigned x0 = v.x & 0xffffu, y0 = v.x >> 16;
            unsigned x1 = v.y & 0xffffu, y1 = v.y >> 16;
            unsigned x2 = v.z & 0xffffu, y2 = v.z >> 16;
            unsigned x3 = v.w & 0xffffu, y3 = v.w >> 16;
            unsigned xl = min(min(x0, x1), min(x2, x3));
            unsigned xh = max(max(x0, x1), max(x2, x3));
            unsigned yl = min(min(y0, y1), min(y2, y3));
            unsigned yh = max(max(y0, y1), max(y2, y3));
            float bw = (float)(xh - xl) * 0.015625f;
            float bh = (float)(yh - yl) * 0.015625f;
            unsigned blx = min(xl / 125u, 511u), bhx = min(xh / 125u, 511u);
            unsigned bly = min(yl / 125u, 511u), bhy = min(yh / 125u, 511u);
            rec[u] = pack_tile_rec(bw, bh, blx, bhx, bly, bhy, &tb[u]);
            rk[u] = atomicAdd(&hist[tb[u]], 1u);
        }
    }
    __syncthreads();
    if (t < NBUCKET) {
        unsigned c = hist[t];
        hbase[t] = c ? atomicAdd(&g_tptr[t], c) : 0u;
    }
    __syncthreads();
    #pragma unroll
    for (int u = 0; u < 4; ++u) {
        if (tb[u] >= 0) {
            unsigned s = hbase[tb[u]] + rk[u];
            if (s < CAP) tslab[(size_t)tb[u] * CAP + s] = rec[u];
        }
    }
}

// ---------------------------------------------------------------------------
// Fallback stage 0: pack pins (r8 path)
// ---------------------------------------------------------------------------
__global__ void pack_kernel(const float* __restrict__ pin_pos,
                            float2* __restrict__ pp) {
    int i = blockIdx.x * blockDim.x + threadIdx.x;
    if (i >= N_PINS / 4) return;
    float4 a = reinterpret_cast<const float4*>(pin_pos)[i];
    float4 b = reinterpret_cast<const float4*>(pin_pos + N_PINS)[i];
    float4* o = reinterpret_cast<float4*>(pp + 4 * (size_t)i);
    o[0] = make_float4(a.x, b.x, a.y, b.y);
    o[1] = make_float4(a.z, b.z, a.w, b.w);
}

// ---------------------------------------------------------------------------
// Fallback gather (r8): direct per-net gather + tile bucketing, f32 bins
// ---------------------------------------------------------------------------
template <bool PACKED>
__device__ __forceinline__ uint2 make_rec_f(const float* __restrict__ pin_pos,
                                            const float2* __restrict__ pp,
                                            int4 fp, int* tb) {
    float2 p0, p1, p2, p3;
    if (PACKED) {
        p0 = pp[fp.x]; p1 = pp[fp.y]; p2 = pp[fp.z]; p3 = pp[fp.w];
    } else {
        p0 = make_float2(pin_pos[fp.x], pin_pos[N_PINS + fp.x]);
        p1 = make_float2(pin_pos[fp.y], pin_pos[N_PINS + fp.y]);
        p2 = make_float2(pin_pos[fp.z], pin_pos[N_PINS + fp.z]);
        p3 = make_float2(pin_pos[fp.w], pin_pos[N_PINS + fp.w]);
    }
    float xl = fminf(fminf(p0.x, p1.x), fminf(p2.x, p3.x));
    float xh = fmaxf(fmaxf(p0.x, p1.x), fmaxf(p2.x, p3.x));
    float yl = fminf(fminf(p0.y, p1.y), fminf(p2.y, p3.y));
    float yh = fmaxf(fmaxf(p0.y, p1.y), fmaxf(p2.y, p3.y));
    unsigned blx = bin_idx(xl), bhx = bin_idx(xh);
    unsigned bly = bin_idx(yl), bhy = bin_idx(yh);
    return pack_tile_rec(xh - xl, yh - yl, blx, bhx, bly, bhy, tb);
}

template <bool PACKED>
__global__ __launch_bounds__(1024)
void gather_bin_kernel(const float* __restrict__ pin_pos,
                       const float2* __restrict__ pp,
                       const int* __restrict__ fnp,
                       uint2* __restrict__ slab,
                       unsigned* __restrict__ g_ptr) {
    __shared__ unsigned hist[NBUCKET];
    __shared__ unsigned hbase[NBUCKET];
    int t = threadIdx.x;
    if (t < NBUCKET) hist[t] = 0;
    __syncthreads();

    int n0 = blockIdx.x * 4096 + t;
    bool v[4]; int4 fp[4]; uint2 r[4]; int b[4]; unsigned rk[4];
    #pragma unroll
    for (int k = 0; k < 4; ++k) {
        int n = n0 + k * 1024;
        v[k] = (n < N_NETS);
        fp[k] = v[k] ? *reinterpret_cast<const int4*>(fnp + 4 * (size_t)n)
                     : make_int4(0, 0, 0, 0);
    }
    #pragma unroll
    for (int k = 0; k < 4; ++k) {
        b[k] = 0;
        if (v[k]) r[k] = make_rec_f<PACKED>(pin_pos, pp, fp[k], &b[k]);
    }
    #pragma unroll
    for (int k = 0; k < 4; ++k) rk[k] = v[k] ? atomicAdd(&hist[b[k]], 1u) : 0u;
    __syncthreads();
    if (t < NBUCKET) {
        unsigned c = hist[t];
        hbase[t] = c ? atomicAdd(&g_ptr[t], c) : 0u;
    }
    __syncthreads();
    #pragma unroll
    for (int k = 0; k < 4; ++k) {
        if (v[k]) {
            unsigned s = hbase[b[k]] + rk[k];
            if (s < CAP) slab[(size_t)b[k] * CAP + s] = r[k];
        }
    }
}

// ---------------------------------------------------------------------------
// Tail (unchanged): accum -> scanA -> scanB -> reduce -> finish -> final
// ---------------------------------------------------------------------------
__device__ __forceinline__ void rec_process(uint2 r, int x0, int y0,
                                            float2* acc) {
    float2 v = __half22float2(*reinterpret_cast<const __half2*>(&r.x));
    unsigned g = r.y;
    int ax0 = (int)(g & 511u);
    int ay0 = (int)((g >> 9) & 511u);
    int ax1 = ax0 + (int)((g >> 18) & 31u);
    int ay1 = ay0 + (int)((g >> 23) & 31u);
    int X0 = ax0 - x0, Y0 = ay0 - y0;
    int X1 = ax1 - x0, Y1 = ay1 - y0;
    bool iX0 = (unsigned)X0 < TILE, iX1 = (unsigned)X1 < TILE;
    bool iY0 = (unsigned)Y0 < TILE, iY1 = (unsigned)Y1 < TILE;
    if (iX0 && iY0) { atomicAdd(&acc[X0 * TILE + Y0].x,  v.x); atomicAdd(&acc[X0 * TILE + Y0].y,  v.y); }
    if (iX1 && iY0) { atomicAdd(&acc[X1 * TILE + Y0].x, -v.x); atomicAdd(&acc[X1 * TILE + Y0].y, -v.y); }
    if (iX0 && iY1) { atomicAdd(&acc[X0 * TILE + Y1].x, -v.x); atomicAdd(&acc[X0 * TILE + Y1].y, -v.y); }
    if (iX1 && iY1) { atomicAdd(&acc[X1 * TILE + Y1].x,  v.x); atomicAdd(&acc[X1 * TILE + Y1].y,  v.y); }
}

__global__ __launch_bounds__(256)
void accum_kernel(const uint2* __restrict__ slab,
                  const unsigned* __restrict__ g_cnt,
                  float2* __restrict__ Dp) {
    __shared__ float2 acc[TILE * TILE];
    int wg = blockIdx.x;
    int sl = wg & (NSLICE - 1), tile = wg >> 2;
    int tx = tile & (NT - 1), ty = tile >> 4;
    int tid = threadIdx.x;

    for (int i = tid; i < TILE * TILE; i += 256) acc[i] = make_float2(0.f, 0.f);
    __syncthreads();

    int x0 = tx * TILE, y0 = ty * TILE;
    #pragma unroll
    for (int dy = -1; dy <= 0; ++dy) {
        int sy = ty + dy; if (sy < 0) continue;
        #pragma unroll
        for (int dx = -1; dx <= 0; ++dx) {
            int sx = tx + dx; if (sx < 0) continue;
            int sb = sy * NT + sx;
            unsigned cnt = min(g_cnt[sb], (unsigned)CAP);
            unsigned lo = (cnt * (unsigned)sl) >> 2;
            unsigned hi = (cnt * (unsigned)(sl + 1)) >> 2;
            const uint2* recs = slab + (size_t)sb * CAP;
            unsigned i = lo + tid;
            for (; i + 768 < hi; i += 1024) {
                uint2 r0 = recs[i];
                uint2 r1 = recs[i + 256];
                uint2 r2 = recs[i + 512];
                uint2 r3 = recs[i + 768];
                rec_process(r0, x0, y0, acc);
                rec_process(r1, x0, y0, acc);
                rec_process(r2, x0, y0, acc);
                rec_process(r3, x0, y0, acc);
            }
            for (; i < hi; i += 256) rec_process(recs[i], x0, y0, acc);
        }
    }
    __syncthreads();

    float2* D = Dp + (size_t)sl * NB * NB;
    for (int i = tid; i < TILE * TILE; i += 256) {
        int X = i >> 5, Y = i & 31;
        D[(size_t)(x0 + X) * NB + (y0 + Y)] = acc[i];
    }
}

__global__ __launch_bounds__(512)
void scanA_kernel(const float2* __restrict__ Dp, float2* __restrict__ S) {
    __shared__ float2 s[NB];
    int x = blockIdx.x, t = threadIdx.x;
    float2 a = make_float2(0.f, 0.f);
    #pragma unroll
    for (int m = 0; m < NMAPS; ++m) {
        float2 v = Dp[(size_t)m * NB * NB + (size_t)x * NB + t];
        a.x += v.x; a.y += v.y;
    }
    s[t] = a;
    __syncthreads();
    for (int off = 1; off < NB; off <<= 1) {
        float2 u = s[t];
        if (t >= off) { float2 w = s[t - off]; u.x += w.x; u.y += w.y; }
        __syncthreads();
        s[t] = u;
        __syncthreads();
    }
    S[(size_t)x * NB + t] = s[t];
}

__global__ __launch_bounds__(512)
void scanB_kernel(float2* __restrict__ S) {
    __shared__ float2 s[NB];
    int y = blockIdx.x, t = threadIdx.x;
    s[t] = S[(size_t)t * NB + y];
    __syncthreads();
    for (int off = 1; off < NB; off <<= 1) {
        float2 u = s[t];
        if (t >= off) { float2 w = s[t - off]; u.x += w.x; u.y += w.y; }
        __syncthreads();
        s[t] = u;
        __syncthreads();
    }
    S[(size_t)t * NB + y] = s[t];
}

__global__ __launch_bounds__(256)
void reduce_kernel(const float* __restrict__ pos,
                   const float* __restrict__ nsx,
                   const float* __restrict__ nsy,
                   const float2* __restrict__ S,
                   double* __restrict__ partials) {
    const int MQ = N_MOVABLE / 4;
    const int TQ = MQ + N_FILLER / 4;
    double a_old = 0.0, a_route = 0.0, a_fill = 0.0;
    int stride = gridDim.x * blockDim.x;
    for (int q = blockIdx.x * blockDim.x + threadIdx.x; q < TQ; q += stride) {
        if (q < MQ) {
            int i = 4 * q;
            float4 x4  = *reinterpret_cast<const float4*>(pos + i);
            float4 y4  = *reinterpret_cast<const float4*>(pos + N_NODES + i);
            float4 sx4 = *reinterpret_cast<const float4*>(nsx + i);
            float4 sy4 = *reinterpret_cast<const float4*>(nsy + i);
            float xs[4] = {x4.x, x4.y, x4.z, x4.w};
            float ys[4] = {y4.x, y4.y, y4.z, y4.w};
            float sxs[4] = {sx4.x, sx4.y, sx4.z, sx4.w};
            float sys[4] = {sy4.x, sy4.y, sy4.z, sy4.w};
            #pragma unroll
            for (int k = 0; k < 4; ++k) {
                int bx = bin_idx(xs[k] + 0.5f * sxs[k]);
                int by = bin_idx(ys[k] + 0.5f * sys[k]);
                float2 u2 = S[(size_t)bx * NB + by];
                float ratio = fminf(fmaxf(fmaxf(u2.x, u2.y), 0.5f), 2.0f);
                float area = sxs[k] * sys[k];
                a_old += (double)area;
                a_route += (double)(area * ratio);
            }
        } else {
            int j = (N_NODES - N_FILLER) + 4 * (q - MQ);
            float4 sx4 = *reinterpret_cast<const float4*>(nsx + j);
            float4 sy4 = *reinterpret_cast<const float4*>(nsy + j);
            a_fill += (double)(sx4.x * sy4.x + sx4.y * sy4.y +
                               sx4.z * sy4.z + sx4.w * sy4.w);
        }
    }
    for (int off = 32; off > 0; off >>= 1) {
        a_old   += __shfl_down(a_old, off);
        a_route += __shfl_down(a_route, off);
        a_fill  += __shfl_down(a_fill, off);
    }
    __shared__ double sd[4][3];
    int wid = threadIdx.x >> 6, lane = threadIdx.x & 63;
    if (lane == 0) { sd[wid][0] = a_old; sd[wid][1] = a_route; sd[wid][2] = a_fill; }
    __syncthreads();
    if (threadIdx.x == 0) {
        double s0 = 0, s1 = 0, s2 = 0;
        for (int w = 0; w < 4; ++w) { s0 += sd[w][0]; s1 += sd[w][1]; s2 += sd[w][2]; }
        partials[blockIdx.x * 3 + 0] = s0;
        partials[blockIdx.x * 3 + 1] = s1;
        partials[blockIdx.x * 3 + 2] = s2;
    }
}

__global__ __launch_bounds__(256)
void finish_kernel(const double* __restrict__ partials,
                   double* __restrict__ sums) {
    int t = threadIdx.x;
    double s0 = 0, s1 = 0, s2 = 0;
    for (int r = t; r < RED_BLOCKS; r += 256) {
        s0 += partials[r * 3 + 0];
        s1 += partials[r * 3 + 1];
        s2 += partials[r * 3 + 2];
    }
    for (int off = 32; off > 0; off >>= 1) {
        s0 += __shfl_down(s0, off);
        s1 += __shfl_down(s1, off);
        s2 += __shfl_down(s2, off);
    }
    __shared__ double sd[4][3];
    int wid = t >> 6, lane = t & 63;
    if (lane == 0) { sd[wid][0] = s0; sd[wid][1] = s1; sd[wid][2] = s2; }
    __syncthreads();
    if (t == 0) {
        double a = 0, b = 0, c = 0;
        for (int w = 0; w < 4; ++w) { a += sd[w][0]; b += sd[w][1]; c += sd[w][2]; }
        sums[0] = a; sums[1] = b; sums[2] = c;
    }
}

__global__ __launch_bounds__(256)
void final_kernel(const float* __restrict__ pos,
                  const float* __restrict__ nsx,
                  const float* __restrict__ nsy,
                  const float2* __restrict__ S,
                  const double* __restrict__ sums,
                  float* __restrict__ out) {
    double sum_area  = sums[0];
    double sum_route = sums[1];
    double fill_old  = sums[2];
    double max_total = sum_area + fill_old;

    float scale = fminf(1.0f, (float)(max_total / fmax(sum_route, 1e-6)));
    float sum_new = (float)(scale * (float)sum_route);
    float fscale = sqrtf(fmaxf((float)max_total - sum_new, 0.0f) /
                         fmaxf((float)fill_old, 1e-6f));

    int q = blockIdx.x * blockDim.x + threadIdx.x;
    if (q >= N_NODES / 4) return;
    int i = 4 * q;

    float4 x4  = *reinterpret_cast<const float4*>(pos + i);
    float4 y4  = *reinterpret_cast<const float4*>(pos + N_NODES + i);
    float4 sx4 = *reinterpret_cast<const float4*>(nsx + i);
    float4 sy4 = *reinterpret_cast<const float4*>(nsy + i);

    float xs[4] = {x4.x, x4.y, x4.z, x4.w};
    float ys[4] = {y4.x, y4.y, y4.z, y4.w};
    float sxs[4] = {sx4.x, sx4.y, sx4.z, sx4.w};
    float sys[4] = {sy4.x, sy4.y, sy4.z, sy4.w};

    if (i < N_MOVABLE) {
        #pragma unroll
        for (int k = 0; k < 4; ++k) {
            int bx = bin_idx(xs[k] + 0.5f * sxs[k]);
            int by = bin_idx(ys[k] + 0.5f * sys[k]);
            float2 u2 = S[(size_t)bx * NB + by];
            float ratio = fminf(fmaxf(fmaxf(u2.x, u2.y), 0.5f), 2.0f);
            float area = sxs[k] * sys[k];
            float new_area = area * ratio * scale;
            float sr = sqrtf(new_area / fmaxf(area, 1e-6f));
            float sx_new = sxs[k] * sr, sy_new = sys[k] * sr;
            xs[k] = xs[k] + 0.5f * (sxs[k] - sx_new);
            ys[k] = ys[k] + 0.5f * (sys[k] - sy_new);
            sxs[k] = sx_new; sys[k] = sy_new;
        }
    } else if (i >= N_NODES - N_FILLER) {
        #pragma unroll
        for (int k = 0; k < 4; ++k) { sxs[k] *= fscale; sys[k] *= fscale; }
    }

    *reinterpret_cast<float4*>(out + i)               = make_float4(xs[0], xs[1], xs[2], xs[3]);
    *reinterpret_cast<float4*>(out + N_NODES + i)     = make_float4(ys[0], ys[1], ys[2], ys[3]);
    *reinterpret_cast<float4*>(out + 2 * N_NODES + i) = make_float4(sxs[0], sxs[1], sxs[2], sxs[3]);
    *reinterpret_cast<float4*>(out + 3 * N_NODES + i) = make_float4(sys[0], sys[1], sys[2], sys[3]);
}

// ---------------------------------------------------------------------------
extern "C" void kernel_launch(void* const* d_in, const int* in_sizes, int n_in,
                              void* d_out, int out_size, void* d_ws, size_t ws_size,
                              hipStream_t stream) {
    const float* pos         = (const float*)d_in[0];
    const float* pin_pos     = (const float*)d_in[1];
    const float* nsx         = (const float*)d_in[2];
    const float* nsy         = (const float*)d_in[3];
    const int*   flat_netpin = (const int*)d_in[4];
    float* out = (float*)d_out;

    const size_t qslab_b = (size_t)N_PINS * sizeof(uint2);            // 48 MB
    const size_t sxy_b   = (size_t)N_PINS * sizeof(unsigned);         // 24 MB
    const size_t tslab_b = (size_t)NBUCKET * CAP * sizeof(uint2);     // 20 MB
    const size_t ctr_b   = 4096;
    const size_t dp_b    = (size_t)NMAPS * NB * NB * sizeof(float2);  // 8 MB
    const size_t s_b     = (size_t)NB * NB * sizeof(float2);          // 2 MB
    const size_t part_b  = (size_t)RED_BLOCKS * 3 * sizeof(double);
    const size_t pp_b    = (size_t)N_PINS * sizeof(float2);           // 48 MB

    const size_t need_new = qslab_b + sxy_b + tslab_b + ctr_b;        // ~92 MB
    const size_t need_r8  = pp_b + tslab_b + ctr_b;                   // ~69 MB

    char* base = (char*)d_ws;
    int tier = (ws_size >= need_new) ? 0 : (ws_size >= need_r8) ? 1 : 2;

    uint2* tslab; unsigned* ctrs; float2* Dp; float2* S;
    double* partials; double* sums;

    if (tier == 0) {
        uint2*    qslab = (uint2*)base;
        unsigned* sxy   = (unsigned*)(base + qslab_b);
        tslab           = (uint2*)(base + qslab_b + sxy_b);
        ctrs            = (unsigned*)(base + qslab_b + sxy_b + tslab_b);
        // tail overlays qslab (dead after p2/p3)
        Dp       = (float2*)base;
        S        = (float2*)(base + dp_b);
        partials = (double*)(base + dp_b + s_b);
        sums     = (double*)(base + dp_b + s_b + part_b);

        unsigned* g_qptr = ctrs;          // 24
        unsigned* g_tptr = ctrs + 448;    // 256

        hipMemsetAsync(ctrs, 0, ctr_b, stream);
        p1_bucketq_kernel<<<(N_PINS + 4095) / 4096, 1024, 0, stream>>>(
            flat_netpin, qslab, g_qptr);
        p2_gather_kernel<<<P2CHUNKS * NXCD, 1024, 0, stream>>>(
            qslab, pin_pos, sxy);
        p3_netrec_kernel<<<(N_NETS + 4095) / 4096, 1024, 0, stream>>>(
            sxy, tslab, g_tptr);
        accum_kernel <<<NBUCKET * NSLICE, 256, 0, stream>>>(tslab, g_tptr, Dp);
    } else if (tier == 1) {
        float2* pp = (float2*)base;
        tslab      = (uint2*)(base + pp_b);
        ctrs       = (unsigned*)(base + pp_b + tslab_b);
        Dp       = (float2*)base;          // overlay pp after gather
        S        = (float2*)(base + dp_b);
        partials = (double*)(base + dp_b + s_b);
        sums     = (double*)(base + dp_b + s_b + part_b);
        unsigned* g_tptr = ctrs + 448;

        hipMemsetAsync(ctrs, 0, ctr_b, stream);
        pack_kernel<<<(N_PINS / 4 + 255) / 256, 256, 0, stream>>>(pin_pos, pp);
        gather_bin_kernel<true><<<(N_NETS + 4095) / 4096, 1024, 0, stream>>>(
            pin_pos, pp, flat_netpin, tslab, g_tptr);
        accum_kernel <<<NBUCKET * NSLICE, 256, 0, stream>>>(tslab, g_tptr, Dp);
    } else {
        tslab = (uint2*)base;
        Dp    = (float2*)(base + tslab_b);
        S     = (float2*)(base + tslab_b + dp_b);
        partials = (double*)(base + tslab_b + dp_b + s_b);
        sums     = (double*)(base + tslab_b + dp_b + s_b + part_b);
        ctrs     = (unsigned*)(base + tslab_b + dp_b + s_b + part_b + 64);
        unsigned* g_tptr = ctrs + 448;

        hipMemsetAsync(ctrs, 0, ctr_b, stream);
        gather_bin_kernel<false><<<(N_NETS + 4095) / 4096, 1024, 0, stream>>>(
            pin_pos, nullptr, flat_netpin, tslab, g_tptr);
        accum_kernel <<<NBUCKET * NSLICE, 256, 0, stream>>>(tslab, g_tptr, Dp);
    }

    scanA_kernel <<<NB, 512, 0, stream>>>(Dp, S);
    scanB_kernel <<<NB, 512, 0, stream>>>(S);
    reduce_kernel<<<RED_BLOCKS, 256, 0, stream>>>(pos, nsx, nsy, S, partials);
    finish_kernel<<<1, 256, 0, stream>>>(partials, sums);
    final_kernel <<<(N_NODES / 4 + 255) / 256, 256, 0, stream>>>(pos, nsx, nsy, S, sums, out);
}

// Round 11
// 257.088 us; speedup vs baseline: 1.0223x; 1.0223x over previous
//
#include <hip/hip_runtime.h>
#include <hip/hip_fp16.h>
#include <math.h>

#define N_NODES   2000000
#define N_MOVABLE 1500000
#define N_FILLER  400000
#define N_NETS    1500000
#define N_PINS    (N_NETS * 4)          // 6,000,000
#define NB        512                   // bins per axis (cropped map)
#define NT        16                    // tiles per axis
#define TILE      32                    // bins per tile axis
#define NBUCKET   (NT * NT)             // 256 tile buckets
#define CAP       10240                 // tile slab capacity per bucket
#define NSLICE    4
#define NMAPS     NSLICE
#define RED_BLOCKS 1024

// --- q-partition (p1/p2) ---
#define NQ        24                    // q-ranges
#define QRNG      250000                // pins per range (24*250k = 6M exact)
#define NXCD      8
#define RPX       3                     // ranges per XCD
#define PIN_PER_XCD (QRNG * RPX)        // 750,000
#define P2CHUNK   4096
#define P2CHUNKS  ((PIN_PER_XCD + P2CHUNK - 1) / P2CHUNK)   // 184

// --- slot-windows (pd/pc) ---
#define SB_SHIFT  14
#define SB_SLOTS  16384                 // slots per window (4096 nets)
#define NSB       ((N_PINS + SB_SLOTS - 1) / SB_SLOTS)      // 367

__device__ __forceinline__ int bin_idx(float v) {
    // BIN_W = 1000/512 = 1.953125 exactly
    float b = floorf(v / 1.953125f);
    b = fminf(fmaxf(b, 0.0f), 511.0f);
    return (int)b;
}

// ---------------------------------------------------------------------------
// P1: bucket (q, slot) by q-range. Coalesced fnp read, LDS-ranked write.
// ---------------------------------------------------------------------------
__global__ __launch_bounds__(1024)
void p1_bucketq_kernel(const int* __restrict__ fnp,
                       uint2* __restrict__ qslab,
                       unsigned* __restrict__ g_qptr) {
    __shared__ unsigned hist[NQ];
    __shared__ unsigned hbase[NQ];
    int t = threadIdx.x;
    if (t < NQ) hist[t] = 0;
    __syncthreads();

    int s0 = blockIdx.x * 4096 + t * 4;
    unsigned q[4]; unsigned qb[4]; unsigned rk[4]; bool val[4];
    if (s0 + 3 < N_PINS) {
        int4 f = *reinterpret_cast<const int4*>(fnp + s0);
        q[0] = (unsigned)f.x; q[1] = (unsigned)f.y;
        q[2] = (unsigned)f.z; q[3] = (unsigned)f.w;
        val[0] = val[1] = val[2] = val[3] = true;
    } else {
        #pragma unroll
        for (int j = 0; j < 4; ++j) {
            val[j] = (s0 + j < N_PINS);
            q[j] = val[j] ? (unsigned)fnp[s0 + j] : 0u;
        }
    }
    #pragma unroll
    for (int j = 0; j < 4; ++j) {
        qb[j] = q[j] / (unsigned)QRNG;
        rk[j] = val[j] ? atomicAdd(&hist[qb[j]], 1u) : 0u;
    }
    __syncthreads();
    if (t < NQ) {
        unsigned c = hist[t];
        hbase[t] = c ? atomicAdd(&g_qptr[t], c) : 0u;
    }
    __syncthreads();
    #pragma unroll
    for (int j = 0; j < 4; ++j) {
        if (val[j]) {
            unsigned idx = qb[j] * (unsigned)QRNG + hbase[qb[j]] + rk[j];
            qslab[idx] = make_uint2(q[j], (unsigned)(s0 + j));
        }
    }
}

// ---------------------------------------------------------------------------
// P2': XCD-affine gather, IN-PLACE rewrite. Blocks with bid%8==k cover ranges
// {k, k+8, k+16} (chunk = bid>>3): the 2MB pin region per range is fetched by
// ONE XCD and gathers L2-hit. Each qslab entry is read and rewritten by
// exactly one thread (race-free): (q, slot) -> (slot, xq|yq<<16).
// Coalesced read AND write; no hist, no scatter.
// ---------------------------------------------------------------------------
__global__ __launch_bounds__(1024)
void p2_gather_kernel(uint2* __restrict__ qslab,
                      const float* __restrict__ pin_pos) {
    unsigned k = blockIdx.x & (NXCD - 1);
    unsigned c = blockIdx.x >> 3;
    unsigned t = threadIdx.x;
    #pragma unroll
    for (int j = 0; j < 4; ++j) {
        unsigned s = c * (unsigned)P2CHUNK + t + (unsigned)j * 1024u;
        if (s < (unsigned)PIN_PER_XCD) {
            unsigned rl = s / (unsigned)QRNG;          // 0..2
            unsigned ridx = s - rl * (unsigned)QRNG;
            unsigned idx = (k + 8u * rl) * (unsigned)QRNG + ridx;
            uint2 qr = qslab[idx];
            float x = pin_pos[qr.x];
            float y = pin_pos[qr.x + N_PINS];
            unsigned xq = __float2uint_rn(x * 64.0f);
            unsigned yq = __float2uint_rn(y * 64.0f);
            qslab[idx] = make_uint2(qr.y, xq | (yq << 16));
        }
    }
}

// ---------------------------------------------------------------------------
// PD: bucket (slot, xy) records by 16384-slot window. Coalesced read,
// LDS-ranked semi-coalesced write (p1's proven pattern, 367 entries).
// ---------------------------------------------------------------------------
__global__ __launch_bounds__(1024)
void pd_bucket_kernel(const uint2* __restrict__ qslab,
                      uint2* __restrict__ sslab,
                      unsigned* __restrict__ g_sptr) {
    __shared__ unsigned hist[NSB];
    __shared__ unsigned hbase[NSB];
    int t = threadIdx.x;
    for (int i = t; i < NSB; i += 1024) hist[i] = 0;
    __syncthreads();

    int i0 = blockIdx.x * 4096 + t;
    uint2 rc[4]; int sb[4]; unsigned rk[4]; bool val[4];
    #pragma unroll
    for (int j = 0; j < 4; ++j) {
        int i = i0 + j * 1024;
        val[j] = (i < N_PINS);
        sb[j] = 0; rk[j] = 0;
        if (val[j]) {
            rc[j] = qslab[i];
            sb[j] = (int)(rc[j].x >> SB_SHIFT);
            rk[j] = atomicAdd(&hist[sb[j]], 1u);
        }
    }
    __syncthreads();
    for (int i = t; i < NSB; i += 1024) {
        unsigned c = hist[i];
        hbase[i] = c ? atomicAdd(&g_sptr[i], c) : 0u;
    }
    __syncthreads();
    #pragma unroll
    for (int j = 0; j < 4; ++j) {
        if (val[j])
            sslab[(size_t)sb[j] * SB_SLOTS + hbase[sb[j]] + rk[j]] = rc[j];
    }
}

// ---------------------------------------------------------------------------
// Per-net 8-byte tile record:
//   .x = f16x2 {vh, vv};  .y = blx | bly<<9 | spanx<<18 | spany<<23
// ---------------------------------------------------------------------------
__device__ __forceinline__ uint2 pack_tile_rec(float bw, float bh,
                                               unsigned blx, unsigned bhx,
                                               unsigned bly, unsigned bhy,
                                               int* tb) {
    float barea = fmaxf(bw * bh, 1e-6f);
    float vh = fminf((bw / barea) * (1.0f / 1.5f), 60000.0f);
    float vv = fminf((bh / barea) * (1.0f / 1.5f), 60000.0f);
    *tb = (int)((bly >> 5) * NT + (blx >> 5));
    __half2 h = __float22half2_rn(make_float2(vh, vv));
    uint2 r;
    r.x = *reinterpret_cast<unsigned*>(&h);
    r.y = blx | (bly << 9) | ((bhx + 1 - blx) << 18) | ((bhy + 1 - bly) << 23);
    return r;
}

// ---------------------------------------------------------------------------
// PC: per-window LDS assembly. Slots within a window are unique (permutation)
// -> plain LDS scatter (no init, no atomics). Net n = 4 consecutive slots ->
// uint4 LDS read -> integer bbox (125 quanta/bin, exact) -> tile records.
// ---------------------------------------------------------------------------
__global__ __launch_bounds__(512)
void pc_window_kernel(const uint2* __restrict__ sslab,
                      uint2* __restrict__ tslab,
                      unsigned* __restrict__ g_tptr) {
    __shared__ unsigned win[SB_SLOTS];        // 64 KB
    __shared__ unsigned hist[NBUCKET];
    __shared__ unsigned hbase[NBUCKET];
    int w = blockIdx.x, t = threadIdx.x;
    int base_slot = w * SB_SLOTS;
    int cnt = min(SB_SLOTS, N_PINS - base_slot);

    if (t < NBUCKET) hist[t] = 0;
    for (int i = t; i < cnt; i += 512) {
        uint2 rc = sslab[(size_t)base_slot + i];
        win[rc.x - (unsigned)base_slot] = rc.y;
    }
    __syncthreads();

    int nets = cnt >> 2;                       // window is net-aligned
    int base_net = w * (SB_SLOTS / 4);
    (void)base_net;
    uint2 rec[8]; int tb[8]; unsigned rk[8];
    #pragma unroll
    for (int u = 0; u < 8; ++u) {
        int j = t + u * 512;
        tb[u] = -1;
        if (j < nets) {
            uint4 v = *reinterpret_cast<const uint4*>(win + 4 * j);
            unsigned x0 = v.x & 0xffffu, y0 = v.x >> 16;
            unsigned x1 = v.y & 0xffffu, y1 = v.y >> 16;
            unsigned x2 = v.z & 0xffffu, y2 = v.z >> 16;
            unsigned x3 = v.w & 0xffffu, y3 = v.w >> 16;
            unsigned xl = min(min(x0, x1), min(x2, x3));
            unsigned xh = max(max(x0, x1), max(x2, x3));
            unsigned yl = min(min(y0, y1), min(y2, y3));
            unsigned yh = max(max(y0, y1), max(y2, y3));
            float bw = (float)(xh - xl) * 0.015625f;
            float bh = (float)(yh - yl) * 0.015625f;
            unsigned blx = min(xl / 125u, 511u), bhx = min(xh / 125u, 511u);
            unsigned bly = min(yl / 125u, 511u), bhy = min(yh / 125u, 511u);
            rec[u] = pack_tile_rec(bw, bh, blx, bhx, bly, bhy, &tb[u]);
            rk[u] = atomicAdd(&hist[tb[u]], 1u);
        }
    }
    __syncthreads();
    if (t < NBUCKET) {
        unsigned c = hist[t];
        hbase[t] = c ? atomicAdd(&g_tptr[t], c) : 0u;
    }
    __syncthreads();
    #pragma unroll
    for (int u = 0; u < 8; ++u) {
        if (tb[u] >= 0) {
            unsigned s = hbase[tb[u]] + rk[u];
            if (s < CAP) tslab[(size_t)tb[u] * CAP + s] = rec[u];
        }
    }
}

// ---------------------------------------------------------------------------
// Fallback (r8 path): pack f32 pins + direct gather
// ---------------------------------------------------------------------------
__global__ void pack_kernel(const float* __restrict__ pin_pos,
                            float2* __restrict__ pp) {
    int i = blockIdx.x * blockDim.x + threadIdx.x;
    if (i >= N_PINS / 4) return;
    float4 a = reinterpret_cast<const float4*>(pin_pos)[i];
    float4 b = reinterpret_cast<const float4*>(pin_pos + N_PINS)[i];
    float4* o = reinterpret_cast<float4*>(pp + 4 * (size_t)i);
    o[0] = make_float4(a.x, b.x, a.y, b.y);
    o[1] = make_float4(a.z, b.z, a.w, b.w);
}

template <bool PACKED>
__device__ __forceinline__ uint2 make_rec_f(const float* __restrict__ pin_pos,
                                            const float2* __restrict__ pp,
                                            int4 fp, int* tb) {
    float2 p0, p1, p2, p3;
    if (PACKED) {
        p0 = pp[fp.x]; p1 = pp[fp.y]; p2 = pp[fp.z]; p3 = pp[fp.w];
    } else {
        p0 = make_float2(pin_pos[fp.x], pin_pos[N_PINS + fp.x]);
        p1 = make_float2(pin_pos[fp.y], pin_pos[N_PINS + fp.y]);
        p2 = make_float2(pin_pos[fp.z], pin_pos[N_PINS + fp.z]);
        p3 = make_float2(pin_pos[fp.w], pin_pos[N_PINS + fp.w]);
    }
    float xl = fminf(fminf(p0.x, p1.x), fminf(p2.x, p3.x));
    float xh = fmaxf(fmaxf(p0.x, p1.x), fmaxf(p2.x, p3.x));
    float yl = fminf(fminf(p0.y, p1.y), fminf(p2.y, p3.y));
    float yh = fmaxf(fmaxf(p0.y, p1.y), fmaxf(p2.y, p3.y));
    unsigned blx = bin_idx(xl), bhx = bin_idx(xh);
    unsigned bly = bin_idx(yl), bhy = bin_idx(yh);
    return pack_tile_rec(xh - xl, yh - yl, blx, bhx, bly, bhy, tb);
}

template <bool PACKED>
__global__ __launch_bounds__(1024)
void gather_bin_kernel(const float* __restrict__ pin_pos,
                       const float2* __restrict__ pp,
                       const int* __restrict__ fnp,
                       uint2* __restrict__ slab,
                       unsigned* __restrict__ g_ptr) {
    __shared__ unsigned hist[NBUCKET];
    __shared__ unsigned hbase[NBUCKET];
    int t = threadIdx.x;
    if (t < NBUCKET) hist[t] = 0;
    __syncthreads();

    int n0 = blockIdx.x * 4096 + t;
    bool v[4]; int4 fp[4]; uint2 r[4]; int b[4]; unsigned rk[4];
    #pragma unroll
    for (int k = 0; k < 4; ++k) {
        int n = n0 + k * 1024;
        v[k] = (n < N_NETS);
        fp[k] = v[k] ? *reinterpret_cast<const int4*>(fnp + 4 * (size_t)n)
                     : make_int4(0, 0, 0, 0);
    }
    #pragma unroll
    for (int k = 0; k < 4; ++k) {
        b[k] = 0;
        if (v[k]) r[k] = make_rec_f<PACKED>(pin_pos, pp, fp[k], &b[k]);
    }
    #pragma unroll
    for (int k = 0; k < 4; ++k) rk[k] = v[k] ? atomicAdd(&hist[b[k]], 1u) : 0u;
    __syncthreads();
    if (t < NBUCKET) {
        unsigned c = hist[t];
        hbase[t] = c ? atomicAdd(&g_ptr[t], c) : 0u;
    }
    __syncthreads();
    #pragma unroll
    for (int k = 0; k < 4; ++k) {
        if (v[k]) {
            unsigned s = hbase[b[k]] + rk[k];
            if (s < CAP) slab[(size_t)b[k] * CAP + s] = r[k];
        }
    }
}

// ---------------------------------------------------------------------------
// Tail (unchanged): accum -> scanA -> scanB -> reduce -> finish -> final
// ---------------------------------------------------------------------------
__device__ __forceinline__ void rec_process(uint2 r, int x0, int y0,
                                            float2* acc) {
    float2 v = __half22float2(*reinterpret_cast<const __half2*>(&r.x));
    unsigned g = r.y;
    int ax0 = (int)(g & 511u);
    int ay0 = (int)((g >> 9) & 511u);
    int ax1 = ax0 + (int)((g >> 18) & 31u);
    int ay1 = ay0 + (int)((g >> 23) & 31u);
    int X0 = ax0 - x0, Y0 = ay0 - y0;
    int X1 = ax1 - x0, Y1 = ay1 - y0;
    bool iX0 = (unsigned)X0 < TILE, iX1 = (unsigned)X1 < TILE;
    bool iY0 = (unsigned)Y0 < TILE, iY1 = (unsigned)Y1 < TILE;
    if (iX0 && iY0) { atomicAdd(&acc[X0 * TILE + Y0].x,  v.x); atomicAdd(&acc[X0 * TILE + Y0].y,  v.y); }
    if (iX1 && iY0) { atomicAdd(&acc[X1 * TILE + Y0].x, -v.x); atomicAdd(&acc[X1 * TILE + Y0].y, -v.y); }
    if (iX0 && iY1) { atomicAdd(&acc[X0 * TILE + Y1].x, -v.x); atomicAdd(&acc[X0 * TILE + Y1].y, -v.y); }
    if (iX1 && iY1) { atomicAdd(&acc[X1 * TILE + Y1].x,  v.x); atomicAdd(&acc[X1 * TILE + Y1].y,  v.y); }
}

__global__ __launch_bounds__(256)
void accum_kernel(const uint2* __restrict__ slab,
                  const unsigned* __restrict__ g_cnt,
                  float2* __restrict__ Dp) {
    __shared__ float2 acc[TILE * TILE];
    int wg = blockIdx.x;
    int sl = wg & (NSLICE - 1), tile = wg >> 2;
    int tx = tile & (NT - 1), ty = tile >> 4;
    int tid = threadIdx.x;

    for (int i = tid; i < TILE * TILE; i += 256) acc[i] = make_float2(0.f, 0.f);
    __syncthreads();

    int x0 = tx * TILE, y0 = ty * TILE;
    #pragma unroll
    for (int dy = -1; dy <= 0; ++dy) {
        int sy = ty + dy; if (sy < 0) continue;
        #pragma unroll
        for (int dx = -1; dx <= 0; ++dx) {
            int sx = tx + dx; if (sx < 0) continue;
            int sb = sy * NT + sx;
            unsigned cnt = min(g_cnt[sb], (unsigned)CAP);
            unsigned lo = (cnt * (unsigned)sl) >> 2;
            unsigned hi = (cnt * (unsigned)(sl + 1)) >> 2;
            const uint2* recs = slab + (size_t)sb * CAP;
            unsigned i = lo + tid;
            for (; i + 768 < hi; i += 1024) {
                uint2 r0 = recs[i];
                uint2 r1 = recs[i + 256];
                uint2 r2 = recs[i + 512];
                uint2 r3 = recs[i + 768];
                rec_process(r0, x0, y0, acc);
                rec_process(r1, x0, y0, acc);
                rec_process(r2, x0, y0, acc);
                rec_process(r3, x0, y0, acc);
            }
            for (; i < hi; i += 256) rec_process(recs[i], x0, y0, acc);
        }
    }
    __syncthreads();

    float2* D = Dp + (size_t)sl * NB * NB;
    for (int i = tid; i < TILE * TILE; i += 256) {
        int X = i >> 5, Y = i & 31;
        D[(size_t)(x0 + X) * NB + (y0 + Y)] = acc[i];
    }
}

__global__ __launch_bounds__(512)
void scanA_kernel(const float2* __restrict__ Dp, float2* __restrict__ S) {
    __shared__ float2 s[NB];
    int x = blockIdx.x, t = threadIdx.x;
    float2 a = make_float2(0.f, 0.f);
    #pragma unroll
    for (int m = 0; m < NMAPS; ++m) {
        float2 v = Dp[(size_t)m * NB * NB + (size_t)x * NB + t];
        a.x += v.x; a.y += v.y;
    }
    s[t] = a;
    __syncthreads();
    for (int off = 1; off < NB; off <<= 1) {
        float2 u = s[t];
        if (t >= off) { float2 w = s[t - off]; u.x += w.x; u.y += w.y; }
        __syncthreads();
        s[t] = u;
        __syncthreads();
    }
    S[(size_t)x * NB + t] = s[t];
}

__global__ __launch_bounds__(512)
void scanB_kernel(float2* __restrict__ S) {
    __shared__ float2 s[NB];
    int y = blockIdx.x, t = threadIdx.x;
    s[t] = S[(size_t)t * NB + y];
    __syncthreads();
    for (int off = 1; off < NB; off <<= 1) {
        float2 u = s[t];
        if (t >= off) { float2 w = s[t - off]; u.x += w.x; u.y += w.y; }
        __syncthreads();
        s[t] = u;
        __syncthreads();
    }
    S[(size_t)t * NB + y] = s[t];
}

__global__ __launch_bounds__(256)
void reduce_kernel(const float* __restrict__ pos,
                   const float* __restrict__ nsx,
                   const float* __restrict__ nsy,
                   const float2* __restrict__ S,
                   double* __restrict__ partials) {
    const int MQ = N_MOVABLE / 4;
    const int TQ = MQ + N_FILLER / 4;
    double a_old = 0.0, a_route = 0.0, a_fill = 0.0;
    int stride = gridDim.x * blockDim.x;
    for (int q = blockIdx.x * blockDim.x + threadIdx.x; q < TQ; q += stride) {
        if (q < MQ) {
            int i = 4 * q;
            float4 x4  = *reinterpret_cast<const float4*>(pos + i);
            float4 y4  = *reinterpret_cast<const float4*>(pos + N_NODES + i);
            float4 sx4 = *reinterpret_cast<const float4*>(nsx + i);
            float4 sy4 = *reinterpret_cast<const float4*>(nsy + i);
            float xs[4] = {x4.x, x4.y, x4.z, x4.w};
            float ys[4] = {y4.x, y4.y, y4.z, y4.w};
            float sxs[4] = {sx4.x, sx4.y, sx4.z, sx4.w};
            float sys[4] = {sy4.x, sy4.y, sy4.z, sy4.w};
            #pragma unroll
            for (int k = 0; k < 4; ++k) {
                int bx = bin_idx(xs[k] + 0.5f * sxs[k]);
                int by = bin_idx(ys[k] + 0.5f * sys[k]);
                float2 u2 = S[(size_t)bx * NB + by];
                float ratio = fminf(fmaxf(fmaxf(u2.x, u2.y), 0.5f), 2.0f);
                float area = sxs[k] * sys[k];
                a_old += (double)area;
                a_route += (double)(area * ratio);
            }
        } else {
            int j = (N_NODES - N_FILLER) + 4 * (q - MQ);
            float4 sx4 = *reinterpret_cast<const float4*>(nsx + j);
            float4 sy4 = *reinterpret_cast<const float4*>(nsy + j);
            a_fill += (double)(sx4.x * sy4.x + sx4.y * sy4.y +
                               sx4.z * sy4.z + sx4.w * sy4.w);
        }
    }
    for (int off = 32; off > 0; off >>= 1) {
        a_old   += __shfl_down(a_old, off);
        a_route += __shfl_down(a_route, off);
        a_fill  += __shfl_down(a_fill, off);
    }
    __shared__ double sd[4][3];
    int wid = threadIdx.x >> 6, lane = threadIdx.x & 63;
    if (lane == 0) { sd[wid][0] = a_old; sd[wid][1] = a_route; sd[wid][2] = a_fill; }
    __syncthreads();
    if (threadIdx.x == 0) {
        double s0 = 0, s1 = 0, s2 = 0;
        for (int w = 0; w < 4; ++w) { s0 += sd[w][0]; s1 += sd[w][1]; s2 += sd[w][2]; }
        partials[blockIdx.x * 3 + 0] = s0;
        partials[blockIdx.x * 3 + 1] = s1;
        partials[blockIdx.x * 3 + 2] = s2;
    }
}

__global__ __launch_bounds__(256)
void finish_kernel(const double* __restrict__ partials,
                   double* __restrict__ sums) {
    int t = threadIdx.x;
    double s0 = 0, s1 = 0, s2 = 0;
    for (int r = t; r < RED_BLOCKS; r += 256) {
        s0 += partials[r * 3 + 0];
        s1 += partials[r * 3 + 1];
        s2 += partials[r * 3 + 2];
    }
    for (int off = 32; off > 0; off >>= 1) {
        s0 += __shfl_down(s0, off);
        s1 += __shfl_down(s1, off);
        s2 += __shfl_down(s2, off);
    }
    __shared__ double sd[4][3];
    int wid = t >> 6, lane = t & 63;
    if (lane == 0) { sd[wid][0] = s0; sd[wid][1] = s1; sd[wid][2] = s2; }
    __syncthreads();
    if (t == 0) {
        double a = 0, b = 0, c = 0;
        for (int w = 0; w < 4; ++w) { a += sd[w][0]; b += sd[w][1]; c += sd[w][2]; }
        sums[0] = a; sums[1] = b; sums[2] = c;
    }
}

__global__ __launch_bounds__(256)
void final_kernel(const float* __restrict__ pos,
                  const float* __restrict__ nsx,
                  const float* __restrict__ nsy,
                  const float2* __restrict__ S,
                  const double* __restrict__ sums,
                  float* __restrict__ out) {
    double sum_area  = sums[0];
    double sum_route = sums[1];
    double fill_old  = sums[2];
    double max_total = sum_area + fill_old;

    float scale = fminf(1.0f, (float)(max_total / fmax(sum_route, 1e-6)));
    float sum_new = (float)(scale * (float)sum_route);
    float fscale = sqrtf(fmaxf((float)max_total - sum_new, 0.0f) /
                         fmaxf((float)fill_old, 1e-6f));

    int q = blockIdx.x * blockDim.x + threadIdx.x;
    if (q >= N_NODES / 4) return;
    int i = 4 * q;

    float4 x4  = *reinterpret_cast<const float4*>(pos + i);
    float4 y4  = *reinterpret_cast<const float4*>(pos + N_NODES + i);
    float4 sx4 = *reinterpret_cast<const float4*>(nsx + i);
    float4 sy4 = *reinterpret_cast<const float4*>(nsy + i);

    float xs[4] = {x4.x, x4.y, x4.z, x4.w};
    float ys[4] = {y4.x, y4.y, y4.z, y4.w};
    float sxs[4] = {sx4.x, sx4.y, sx4.z, sx4.w};
    float sys[4] = {sy4.x, sy4.y, sy4.z, sy4.w};

    if (i < N_MOVABLE) {
        #pragma unroll
        for (int k = 0; k < 4; ++k) {
            int bx = bin_idx(xs[k] + 0.5f * sxs[k]);
            int by = bin_idx(ys[k] + 0.5f * sys[k]);
            float2 u2 = S[(size_t)bx * NB + by];
            float ratio = fminf(fmaxf(fmaxf(u2.x, u2.y), 0.5f), 2.0f);
            float area = sxs[k] * sys[k];
            float new_area = area * ratio * scale;
            float sr = sqrtf(new_area / fmaxf(area, 1e-6f));
            float sx_new = sxs[k] * sr, sy_new = sys[k] * sr;
            xs[k] = xs[k] + 0.5f * (sxs[k] - sx_new);
            ys[k] = ys[k] + 0.5f * (sys[k] - sy_new);
            sxs[k] = sx_new; sys[k] = sy_new;
        }
    } else if (i >= N_NODES - N_FILLER) {
        #pragma unroll
        for (int k = 0; k < 4; ++k) { sxs[k] *= fscale; sys[k] *= fscale; }
    }

    *reinterpret_cast<float4*>(out + i)               = make_float4(xs[0], xs[1], xs[2], xs[3]);
    *reinterpret_cast<float4*>(out + N_NODES + i)     = make_float4(ys[0], ys[1], ys[2], ys[3]);
    *reinterpret_cast<float4*>(out + 2 * N_NODES + i) = make_float4(sxs[0], sxs[1], sxs[2], sxs[3]);
    *reinterpret_cast<float4*>(out + 3 * N_NODES + i) = make_float4(sys[0], sys[1], sys[2], sys[3]);
}

// ---------------------------------------------------------------------------
extern "C" void kernel_launch(void* const* d_in, const int* in_sizes, int n_in,
                              void* d_out, int out_size, void* d_ws, size_t ws_size,
                              hipStream_t stream) {
    const float* pos         = (const float*)d_in[0];
    const float* pin_pos     = (const float*)d_in[1];
    const float* nsx         = (const float*)d_in[2];
    const float* nsy         = (const float*)d_in[3];
    const int*   flat_netpin = (const int*)d_in[4];
    float* out = (float*)d_out;

    const size_t qslab_b = (size_t)N_PINS * sizeof(uint2);            // 48 MB
    const size_t sslab_b = (size_t)NSB * SB_SLOTS * sizeof(uint2);    // 48.1 MB
    const size_t tslab_b = (size_t)NBUCKET * CAP * sizeof(uint2);     // 20 MB
    const size_t ctr_b   = 4096;
    const size_t dp_b    = (size_t)NMAPS * NB * NB * sizeof(float2);  // 8 MB
    const size_t s_b     = (size_t)NB * NB * sizeof(float2);          // 2 MB
    const size_t part_b  = (size_t)RED_BLOCKS * 3 * sizeof(double);
    const size_t pp_b    = (size_t)N_PINS * sizeof(float2);           // 48 MB

    const size_t need_new = qslab_b + sslab_b + tslab_b + ctr_b;      // ~116 MB
    const size_t need_r8  = pp_b + tslab_b + ctr_b;                   // ~69 MB

    char* base = (char*)d_ws;
    int tier = (ws_size >= need_new) ? 0 : (ws_size >= need_r8) ? 1 : 2;

    uint2* tslab; unsigned* ctrs; float2* Dp; float2* S;
    double* partials; double* sums;

    if (tier == 0) {
        uint2* qslab = (uint2*)base;
        uint2* sslab = (uint2*)(base + qslab_b);
        tslab        = (uint2*)(base + qslab_b + sslab_b);
        ctrs         = (unsigned*)(base + qslab_b + sslab_b + tslab_b);
        // tail overlays qslab (dead after pd)
        Dp       = (float2*)base;
        S        = (float2*)(base + dp_b);
        partials = (double*)(base + dp_b + s_b);
        sums     = (double*)(base + dp_b + s_b + part_b);

        unsigned* g_qptr = ctrs;          // 24
        unsigned* g_sptr = ctrs + 64;     // 367
        unsigned* g_tptr = ctrs + 448;    // 256

        hipMemsetAsync(ctrs, 0, ctr_b, stream);
        p1_bucketq_kernel<<<(N_PINS + 4095) / 4096, 1024, 0, stream>>>(
            flat_netpin, qslab, g_qptr);
        p2_gather_kernel<<<P2CHUNKS * NXCD, 1024, 0, stream>>>(qslab, pin_pos);
        pd_bucket_kernel<<<(N_PINS + 4095) / 4096, 1024, 0, stream>>>(
            qslab, sslab, g_sptr);
        pc_window_kernel<<<NSB, 512, 0, stream>>>(sslab, tslab, g_tptr);
        accum_kernel <<<NBUCKET * NSLICE, 256, 0, stream>>>(tslab, g_tptr, Dp);
    } else if (tier == 1) {
        float2* pp = (float2*)base;
        tslab      = (uint2*)(base + pp_b);
        ctrs       = (unsigned*)(base + pp_b + tslab_b);
        Dp       = (float2*)base;          // overlay pp after gather
        S        = (float2*)(base + dp_b);
        partials = (double*)(base + dp_b + s_b);
        sums     = (double*)(base + dp_b + s_b + part_b);
        unsigned* g_tptr = ctrs + 448;

        hipMemsetAsync(ctrs, 0, ctr_b, stream);
        pack_kernel<<<(N_PINS / 4 + 255) / 256, 256, 0, stream>>>(pin_pos, pp);
        gather_bin_kernel<true><<<(N_NETS + 4095) / 4096, 1024, 0, stream>>>(
            pin_pos, pp, flat_netpin, tslab, g_tptr);
        accum_kernel <<<NBUCKET * NSLICE, 256, 0, stream>>>(tslab, g_tptr, Dp);
    } else {
        tslab = (uint2*)base;
        Dp    = (float2*)(base + tslab_b);
        S     = (float2*)(base + tslab_b + dp_b);
        partials = (double*)(base + tslab_b + dp_b + s_b);
        sums     = (double*)(base + tslab_b + dp_b + s_b + part_b);
        ctrs     = (unsigned*)(base + tslab_b + dp_b + s_b + part_b + 64);
        unsigned* g_tptr = ctrs + 448;

        hipMemsetAsync(ctrs, 0, ctr_b, stream);
        gather_bin_kernel<false><<<(N_NETS + 4095) / 4096, 1024, 0, stream>>>(
            pin_pos, nullptr, flat_netpin, tslab, g_tptr);
        accum_kernel <<<NBUCKET * NSLICE, 256, 0, stream>>>(tslab, g_tptr, Dp);
    }

    scanA_kernel <<<NB, 512, 0, stream>>>(Dp, S);
    scanB_kernel <<<NB, 512, 0, stream>>>(S);
    reduce_kernel<<<RED_BLOCKS, 256, 0, stream>>>(pos, nsx, nsy, S, partials);
    finish_kernel<<<1, 256, 0, stream>>>(partials, sums);
    final_kernel <<<(N_NODES / 4 + 255) / 256, 256, 0, stream>>>(pos, nsx, nsy, S, sums, out);
}

// Round 12
// 219.690 us; speedup vs baseline: 1.1963x; 1.1702x over previous
//
#include <hip/hip_runtime.h>
#include <hip/hip_fp16.h>
#include <math.h>

#define N_NODES   2000000
#define N_MOVABLE 1500000
#define N_FILLER  400000
#define N_NETS    1500000
#define N_PINS    (N_NETS * 4)          // 6,000,000
#define NB        512                   // bins per axis (cropped map)
#define NT        16                    // tiles per axis
#define TILE      32                    // bins per tile axis
#define NBUCKET   (NT * NT)             // 256 tile buckets
#define CAP       10240                 // tile slab capacity per bucket
#define NSLICE    4
#define NMAPS     NSLICE
#define NPB       4096                  // nets per gather block (4/thread)
#define RED_BLOCKS 1024

__device__ __forceinline__ int bin_idx(float v) {
    // BIN_W = 1000/512 = 1.953125 exactly; matches jnp floor(v / BIN_W)
    float b = floorf(v / 1.953125f);
    b = fminf(fmaxf(b, 0.0f), 511.0f);
    return (int)b;
}

// ---------------------------------------------------------------------------
// Stage 0: quantize+pack pins into ONE u32 per pin (xq | yq<<16, 1/64 unit).
// 24 MB array -> 16 pins/line -> per-XCD L2 reuse on the random gather.
// Bin math stays exact: bin width = 125 quanta. Also zeroes counters.
// ---------------------------------------------------------------------------
__global__ __launch_bounds__(256)
void packq_kernel(const float* __restrict__ pin_pos,
                  unsigned* __restrict__ pxy,
                  unsigned* __restrict__ ctrs) {
    if (blockIdx.x == 0 && threadIdx.x < 1024) ctrs[threadIdx.x] = 0u;
    int i = blockIdx.x * blockDim.x + threadIdx.x;
    if (i >= N_PINS / 4) return;
    float4 a = reinterpret_cast<const float4*>(pin_pos)[i];            // x[4i..]
    float4 b = reinterpret_cast<const float4*>(pin_pos + N_PINS)[i];   // y[4i..]
    uint4 o;
    o.x = __float2uint_rn(a.x * 64.0f) | (__float2uint_rn(b.x * 64.0f) << 16);
    o.y = __float2uint_rn(a.y * 64.0f) | (__float2uint_rn(b.y * 64.0f) << 16);
    o.z = __float2uint_rn(a.z * 64.0f) | (__float2uint_rn(b.z * 64.0f) << 16);
    o.w = __float2uint_rn(a.w * 64.0f) | (__float2uint_rn(b.w * 64.0f) << 16);
    reinterpret_cast<uint4*>(pxy)[i] = o;
}

// ---------------------------------------------------------------------------
// Per-net 8-byte tile record:
//   .x = f16x2 {vh, vv};  .y = blx | bly<<9 | spanx<<18 | spany<<23
// ---------------------------------------------------------------------------
__device__ __forceinline__ uint2 pack_tile_rec(float bw, float bh,
                                               unsigned blx, unsigned bhx,
                                               unsigned bly, unsigned bhy,
                                               int* tb) {
    float barea = fmaxf(bw * bh, 1e-6f);
    float vh = fminf((bw / barea) * (1.0f / 1.5f), 60000.0f);
    float vv = fminf((bh / barea) * (1.0f / 1.5f), 60000.0f);
    *tb = (int)((bly >> 5) * NT + (blx >> 5));
    __half2 h = __float22half2_rn(make_float2(vh, vv));
    uint2 r;
    r.x = *reinterpret_cast<unsigned*>(&h);
    r.y = blx | (bly << 9) | ((bhx + 1 - blx) << 18) | ((bhy + 1 - bly) << 23);
    return r;
}

// ---------------------------------------------------------------------------
// Stage 1: per-net gather (4 u32 gathers from 24 MB pxy) -> integer bbox ->
// tile record -> counting-sort into per-tile slabs. 4 nets/thread.
// ---------------------------------------------------------------------------
__global__ __launch_bounds__(1024)
void gather_bin_kernel(const unsigned* __restrict__ pxy,
                       const int* __restrict__ fnp,
                       uint2* __restrict__ slab,
                       unsigned* __restrict__ g_ptr) {
    __shared__ unsigned hist[NBUCKET];
    __shared__ unsigned hbase[NBUCKET];
    int t = threadIdx.x;
    if (t < NBUCKET) hist[t] = 0;
    __syncthreads();

    int n0 = blockIdx.x * NPB + t;
    bool v[4]; int4 fp[4]; uint2 r[4]; int b[4]; unsigned rk[4];
    #pragma unroll
    for (int k = 0; k < 4; ++k) {
        int n = n0 + k * 1024;
        v[k] = (n < N_NETS);
        fp[k] = v[k] ? *reinterpret_cast<const int4*>(fnp + 4 * (size_t)n)
                     : make_int4(0, 0, 0, 0);
    }
    #pragma unroll
    for (int k = 0; k < 4; ++k) {
        b[k] = 0;
        if (v[k]) {
            unsigned p0 = pxy[fp[k].x], p1 = pxy[fp[k].y];
            unsigned p2 = pxy[fp[k].z], p3 = pxy[fp[k].w];
            unsigned x0 = p0 & 0xffffu, y0 = p0 >> 16;
            unsigned x1 = p1 & 0xffffu, y1 = p1 >> 16;
            unsigned x2 = p2 & 0xffffu, y2 = p2 >> 16;
            unsigned x3 = p3 & 0xffffu, y3 = p3 >> 16;
            unsigned xl = min(min(x0, x1), min(x2, x3));
            unsigned xh = max(max(x0, x1), max(x2, x3));
            unsigned yl = min(min(y0, y1), min(y2, y3));
            unsigned yh = max(max(y0, y1), max(y2, y3));
            float bw = (float)(xh - xl) * 0.015625f;
            float bh = (float)(yh - yl) * 0.015625f;
            unsigned blx = min(xl / 125u, 511u), bhx = min(xh / 125u, 511u);
            unsigned bly = min(yl / 125u, 511u), bhy = min(yh / 125u, 511u);
            r[k] = pack_tile_rec(bw, bh, blx, bhx, bly, bhy, &b[k]);
        }
    }
    #pragma unroll
    for (int k = 0; k < 4; ++k) rk[k] = v[k] ? atomicAdd(&hist[b[k]], 1u) : 0u;
    __syncthreads();
    if (t < NBUCKET) {
        unsigned c = hist[t];
        hbase[t] = c ? atomicAdd(&g_ptr[t], c) : 0u;
    }
    __syncthreads();
    #pragma unroll
    for (int k = 0; k < 4; ++k) {
        if (v[k]) {
            unsigned s = hbase[b[k]] + rk[k];
            if (s < CAP) slab[(size_t)b[k] * CAP + s] = r[k];
        }
    }
}

// ---------------------------------------------------------------------------
// Fallback gather (tiny ws): direct f32 gather from pin_pos, f32 bins
// ---------------------------------------------------------------------------
__global__ __launch_bounds__(1024)
void gather_bin_f32_kernel(const float* __restrict__ pin_pos,
                           const int* __restrict__ fnp,
                           uint2* __restrict__ slab,
                           unsigned* __restrict__ g_ptr) {
    __shared__ unsigned hist[NBUCKET];
    __shared__ unsigned hbase[NBUCKET];
    int t = threadIdx.x;
    if (t < NBUCKET) hist[t] = 0;
    __syncthreads();

    int n0 = blockIdx.x * NPB + t;
    bool v[4]; uint2 r[4]; int b[4]; unsigned rk[4];
    #pragma unroll
    for (int k = 0; k < 4; ++k) {
        int n = n0 + k * 1024;
        v[k] = (n < N_NETS);
        b[k] = 0;
        if (v[k]) {
            int4 fp = *reinterpret_cast<const int4*>(fnp + 4 * (size_t)n);
            float px0 = pin_pos[fp.x], px1 = pin_pos[fp.y];
            float px2 = pin_pos[fp.z], px3 = pin_pos[fp.w];
            float py0 = pin_pos[N_PINS + fp.x], py1 = pin_pos[N_PINS + fp.y];
            float py2 = pin_pos[N_PINS + fp.z], py3 = pin_pos[N_PINS + fp.w];
            float xl = fminf(fminf(px0, px1), fminf(px2, px3));
            float xh = fmaxf(fmaxf(px0, px1), fmaxf(px2, px3));
            float yl = fminf(fminf(py0, py1), fminf(py2, py3));
            float yh = fmaxf(fmaxf(py0, py1), fmaxf(py2, py3));
            unsigned blx = bin_idx(xl), bhx = bin_idx(xh);
            unsigned bly = bin_idx(yl), bhy = bin_idx(yh);
            r[k] = pack_tile_rec(xh - xl, yh - yl, blx, bhx, bly, bhy, &b[k]);
        }
    }
    #pragma unroll
    for (int k = 0; k < 4; ++k) rk[k] = v[k] ? atomicAdd(&hist[b[k]], 1u) : 0u;
    __syncthreads();
    if (t < NBUCKET) {
        unsigned c = hist[t];
        hbase[t] = c ? atomicAdd(&g_ptr[t], c) : 0u;
    }
    __syncthreads();
    #pragma unroll
    for (int k = 0; k < 4; ++k) {
        if (v[k]) {
            unsigned s = hbase[b[k]] + rk[k];
            if (s < CAP) slab[(size_t)b[k] * CAP + s] = r[k];
        }
    }
}

// ---------------------------------------------------------------------------
// Tail (unchanged, proven): accum -> scanA -> scanB -> reduce -> finish -> final
// ---------------------------------------------------------------------------
__device__ __forceinline__ void rec_process(uint2 r, int x0, int y0,
                                            float2* acc) {
    float2 v = __half22float2(*reinterpret_cast<const __half2*>(&r.x));
    unsigned g = r.y;
    int ax0 = (int)(g & 511u);
    int ay0 = (int)((g >> 9) & 511u);
    int ax1 = ax0 + (int)((g >> 18) & 31u);
    int ay1 = ay0 + (int)((g >> 23) & 31u);
    int X0 = ax0 - x0, Y0 = ay0 - y0;
    int X1 = ax1 - x0, Y1 = ay1 - y0;
    bool iX0 = (unsigned)X0 < TILE, iX1 = (unsigned)X1 < TILE;
    bool iY0 = (unsigned)Y0 < TILE, iY1 = (unsigned)Y1 < TILE;
    if (iX0 && iY0) { atomicAdd(&acc[X0 * TILE + Y0].x,  v.x); atomicAdd(&acc[X0 * TILE + Y0].y,  v.y); }
    if (iX1 && iY0) { atomicAdd(&acc[X1 * TILE + Y0].x, -v.x); atomicAdd(&acc[X1 * TILE + Y0].y, -v.y); }
    if (iX0 && iY1) { atomicAdd(&acc[X0 * TILE + Y1].x, -v.x); atomicAdd(&acc[X0 * TILE + Y1].y, -v.y); }
    if (iX1 && iY1) { atomicAdd(&acc[X1 * TILE + Y1].x,  v.x); atomicAdd(&acc[X1 * TILE + Y1].y,  v.y); }
}

__global__ __launch_bounds__(256)
void accum_kernel(const uint2* __restrict__ slab,
                  const unsigned* __restrict__ g_cnt,
                  float2* __restrict__ Dp) {
    __shared__ float2 acc[TILE * TILE];
    int wg = blockIdx.x;
    int sl = wg & (NSLICE - 1), tile = wg >> 2;
    int tx = tile & (NT - 1), ty = tile >> 4;
    int tid = threadIdx.x;

    for (int i = tid; i < TILE * TILE; i += 256) acc[i] = make_float2(0.f, 0.f);
    __syncthreads();

    int x0 = tx * TILE, y0 = ty * TILE;
    #pragma unroll
    for (int dy = -1; dy <= 0; ++dy) {
        int sy = ty + dy; if (sy < 0) continue;
        #pragma unroll
        for (int dx = -1; dx <= 0; ++dx) {
            int sx = tx + dx; if (sx < 0) continue;
            int sb = sy * NT + sx;
            unsigned cnt = min(g_cnt[sb], (unsigned)CAP);
            unsigned lo = (cnt * (unsigned)sl) >> 2;
            unsigned hi = (cnt * (unsigned)(sl + 1)) >> 2;
            const uint2* recs = slab + (size_t)sb * CAP;
            unsigned i = lo + tid;
            for (; i + 768 < hi; i += 1024) {
                uint2 r0 = recs[i];
                uint2 r1 = recs[i + 256];
                uint2 r2 = recs[i + 512];
                uint2 r3 = recs[i + 768];
                rec_process(r0, x0, y0, acc);
                rec_process(r1, x0, y0, acc);
                rec_process(r2, x0, y0, acc);
                rec_process(r3, x0, y0, acc);
            }
            for (; i < hi; i += 256) rec_process(recs[i], x0, y0, acc);
        }
    }
    __syncthreads();

    float2* D = Dp + (size_t)sl * NB * NB;
    for (int i = tid; i < TILE * TILE; i += 256) {
        int X = i >> 5, Y = i & 31;
        D[(size_t)(x0 + X) * NB + (y0 + Y)] = acc[i];
    }
}

__global__ __launch_bounds__(512)
void scanA_kernel(const float2* __restrict__ Dp, float2* __restrict__ S) {
    __shared__ float2 s[NB];
    int x = blockIdx.x, t = threadIdx.x;
    float2 a = make_float2(0.f, 0.f);
    #pragma unroll
    for (int m = 0; m < NMAPS; ++m) {
        float2 v = Dp[(size_t)m * NB * NB + (size_t)x * NB + t];
        a.x += v.x; a.y += v.y;
    }
    s[t] = a;
    __syncthreads();
    for (int off = 1; off < NB; off <<= 1) {
        float2 u = s[t];
        if (t >= off) { float2 w = s[t - off]; u.x += w.x; u.y += w.y; }
        __syncthreads();
        s[t] = u;
        __syncthreads();
    }
    S[(size_t)x * NB + t] = s[t];
}

__global__ __launch_bounds__(512)
void scanB_kernel(float2* __restrict__ S) {
    __shared__ float2 s[NB];
    int y = blockIdx.x, t = threadIdx.x;
    s[t] = S[(size_t)t * NB + y];
    __syncthreads();
    for (int off = 1; off < NB; off <<= 1) {
        float2 u = s[t];
        if (t >= off) { float2 w = s[t - off]; u.x += w.x; u.y += w.y; }
        __syncthreads();
        s[t] = u;
        __syncthreads();
    }
    S[(size_t)t * NB + y] = s[t];
}

__global__ __launch_bounds__(256)
void reduce_kernel(const float* __restrict__ pos,
                   const float* __restrict__ nsx,
                   const float* __restrict__ nsy,
                   const float2* __restrict__ S,
                   double* __restrict__ partials) {
    const int MQ = N_MOVABLE / 4;
    const int TQ = MQ + N_FILLER / 4;
    double a_old = 0.0, a_route = 0.0, a_fill = 0.0;
    int stride = gridDim.x * blockDim.x;
    for (int q = blockIdx.x * blockDim.x + threadIdx.x; q < TQ; q += stride) {
        if (q < MQ) {
            int i = 4 * q;
            float4 x4  = *reinterpret_cast<const float4*>(pos + i);
            float4 y4  = *reinterpret_cast<const float4*>(pos + N_NODES + i);
            float4 sx4 = *reinterpret_cast<const float4*>(nsx + i);
            float4 sy4 = *reinterpret_cast<const float4*>(nsy + i);
            float xs[4] = {x4.x, x4.y, x4.z, x4.w};
            float ys[4] = {y4.x, y4.y, y4.z, y4.w};
            float sxs[4] = {sx4.x, sx4.y, sx4.z, sx4.w};
            float sys[4] = {sy4.x, sy4.y, sy4.z, sy4.w};
            #pragma unroll
            for (int k = 0; k < 4; ++k) {
                int bx = bin_idx(xs[k] + 0.5f * sxs[k]);
                int by = bin_idx(ys[k] + 0.5f * sys[k]);
                float2 u2 = S[(size_t)bx * NB + by];
                float ratio = fminf(fmaxf(fmaxf(u2.x, u2.y), 0.5f), 2.0f);
                float area = sxs[k] * sys[k];
                a_old += (double)area;
                a_route += (double)(area * ratio);
            }
        } else {
            int j = (N_NODES - N_FILLER) + 4 * (q - MQ);
            float4 sx4 = *reinterpret_cast<const float4*>(nsx + j);
            float4 sy4 = *reinterpret_cast<const float4*>(nsy + j);
            a_fill += (double)(sx4.x * sy4.x + sx4.y * sy4.y +
                               sx4.z * sy4.z + sx4.w * sy4.w);
        }
    }
    for (int off = 32; off > 0; off >>= 1) {
        a_old   += __shfl_down(a_old, off);
        a_route += __shfl_down(a_route, off);
        a_fill  += __shfl_down(a_fill, off);
    }
    __shared__ double sd[4][3];
    int wid = threadIdx.x >> 6, lane = threadIdx.x & 63;
    if (lane == 0) { sd[wid][0] = a_old; sd[wid][1] = a_route; sd[wid][2] = a_fill; }
    __syncthreads();
    if (threadIdx.x == 0) {
        double s0 = 0, s1 = 0, s2 = 0;
        for (int w = 0; w < 4; ++w) { s0 += sd[w][0]; s1 += sd[w][1]; s2 += sd[w][2]; }
        partials[blockIdx.x * 3 + 0] = s0;
        partials[blockIdx.x * 3 + 1] = s1;
        partials[blockIdx.x * 3 + 2] = s2;
    }
}

__global__ __launch_bounds__(256)
void finish_kernel(const double* __restrict__ partials,
                   double* __restrict__ sums) {
    int t = threadIdx.x;
    double s0 = 0, s1 = 0, s2 = 0;
    for (int r = t; r < RED_BLOCKS; r += 256) {
        s0 += partials[r * 3 + 0];
        s1 += partials[r * 3 + 1];
        s2 += partials[r * 3 + 2];
    }
    for (int off = 32; off > 0; off >>= 1) {
        s0 += __shfl_down(s0, off);
        s1 += __shfl_down(s1, off);
        s2 += __shfl_down(s2, off);
    }
    __shared__ double sd[4][3];
    int wid = t >> 6, lane = t & 63;
    if (lane == 0) { sd[wid][0] = s0; sd[wid][1] = s1; sd[wid][2] = s2; }
    __syncthreads();
    if (t == 0) {
        double a = 0, b = 0, c = 0;
        for (int w = 0; w < 4; ++w) { a += sd[w][0]; b += sd[w][1]; c += sd[w][2]; }
        sums[0] = a; sums[1] = b; sums[2] = c;
    }
}

__global__ __launch_bounds__(256)
void final_kernel(const float* __restrict__ pos,
                  const float* __restrict__ nsx,
                  const float* __restrict__ nsy,
                  const float2* __restrict__ S,
                  const double* __restrict__ sums,
                  float* __restrict__ out) {
    double sum_area  = sums[0];
    double sum_route = sums[1];
    double fill_old  = sums[2];
    double max_total = sum_area + fill_old;

    float scale = fminf(1.0f, (float)(max_total / fmax(sum_route, 1e-6)));
    float sum_new = (float)(scale * (float)sum_route);
    float fscale = sqrtf(fmaxf((float)max_total - sum_new, 0.0f) /
                         fmaxf((float)fill_old, 1e-6f));

    int q = blockIdx.x * blockDim.x + threadIdx.x;
    if (q >= N_NODES / 4) return;
    int i = 4 * q;

    float4 x4  = *reinterpret_cast<const float4*>(pos + i);
    float4 y4  = *reinterpret_cast<const float4*>(pos + N_NODES + i);
    float4 sx4 = *reinterpret_cast<const float4*>(nsx + i);
    float4 sy4 = *reinterpret_cast<const float4*>(nsy + i);

    float xs[4] = {x4.x, x4.y, x4.z, x4.w};
    float ys[4] = {y4.x, y4.y, y4.z, y4.w};
    float sxs[4] = {sx4.x, sx4.y, sx4.z, sx4.w};
    float sys[4] = {sy4.x, sy4.y, sy4.z, sy4.w};

    if (i < N_MOVABLE) {
        #pragma unroll
        for (int k = 0; k < 4; ++k) {
            int bx = bin_idx(xs[k] + 0.5f * sxs[k]);
            int by = bin_idx(ys[k] + 0.5f * sys[k]);
            float2 u2 = S[(size_t)bx * NB + by];
            float ratio = fminf(fmaxf(fmaxf(u2.x, u2.y), 0.5f), 2.0f);
            float area = sxs[k] * sys[k];
            float new_area = area * ratio * scale;
            float sr = sqrtf(new_area / fmaxf(area, 1e-6f));
            float sx_new = sxs[k] * sr, sy_new = sys[k] * sr;
            xs[k] = xs[k] + 0.5f * (sxs[k] - sx_new);
            ys[k] = ys[k] + 0.5f * (sys[k] - sy_new);
            sxs[k] = sx_new; sys[k] = sy_new;
        }
    } else if (i >= N_NODES - N_FILLER) {
        #pragma unroll
        for (int k = 0; k < 4; ++k) { sxs[k] *= fscale; sys[k] *= fscale; }
    }

    *reinterpret_cast<float4*>(out + i)               = make_float4(xs[0], xs[1], xs[2], xs[3]);
    *reinterpret_cast<float4*>(out + N_NODES + i)     = make_float4(ys[0], ys[1], ys[2], ys[3]);
    *reinterpret_cast<float4*>(out + 2 * N_NODES + i) = make_float4(sxs[0], sxs[1], sxs[2], sxs[3]);
    *reinterpret_cast<float4*>(out + 3 * N_NODES + i) = make_float4(sys[0], sys[1], sys[2], sys[3]);
}

// ---------------------------------------------------------------------------
extern "C" void kernel_launch(void* const* d_in, const int* in_sizes, int n_in,
                              void* d_out, int out_size, void* d_ws, size_t ws_size,
                              hipStream_t stream) {
    const float* pos         = (const float*)d_in[0];
    const float* pin_pos     = (const float*)d_in[1];
    const float* nsx         = (const float*)d_in[2];
    const float* nsy         = (const float*)d_in[3];
    const int*   flat_netpin = (const int*)d_in[4];
    float* out = (float*)d_out;

    const size_t pxy_b   = (size_t)N_PINS * sizeof(unsigned);          // 24 MB
    const size_t tslab_b = (size_t)NBUCKET * CAP * sizeof(uint2);      // 20 MB
    const size_t ctr_b   = 4096;
    const size_t dp_b    = (size_t)NMAPS * NB * NB * sizeof(float2);   // 8 MB
    const size_t s_b     = (size_t)NB * NB * sizeof(float2);           // 2 MB
    const size_t part_b  = (size_t)RED_BLOCKS * 3 * sizeof(double);    // 24 KB

    // Primary: [pxy(24) | tslab(20) | ctrs]; tail overlays pxy
    // (dead after gather; dp+s+part+sums = ~10 MB <= 24 MB).
    const size_t need_primary = pxy_b + tslab_b + ctr_b;               // ~44 MB

    char* base = (char*)d_ws;
    bool primary = (ws_size >= need_primary);

    uint2* tslab; unsigned* ctrs; float2* Dp; float2* S;
    double* partials; double* sums;

    const int GB_BLOCKS = (N_NETS + NPB - 1) / NPB;    // 367

    if (primary) {
        unsigned* pxy = (unsigned*)base;
        tslab = (uint2*)(base + pxy_b);
        ctrs  = (unsigned*)(base + pxy_b + tslab_b);
        Dp       = (float2*)base;                       // overlay after gather
        S        = (float2*)(base + dp_b);
        partials = (double*)(base + dp_b + s_b);
        sums     = (double*)(base + dp_b + s_b + part_b);
        unsigned* g_tptr = ctrs;

        packq_kernel<<<(N_PINS / 4 + 255) / 256, 256, 0, stream>>>(
            pin_pos, pxy, ctrs);
        gather_bin_kernel<<<GB_BLOCKS, 1024, 0, stream>>>(
            pxy, flat_netpin, tslab, g_tptr);
        accum_kernel<<<NBUCKET * NSLICE, 256, 0, stream>>>(tslab, g_tptr, Dp);
    } else {
        tslab = (uint2*)base;
        Dp    = (float2*)(base + tslab_b);
        S     = (float2*)(base + tslab_b + dp_b);
        partials = (double*)(base + tslab_b + dp_b + s_b);
        sums     = (double*)(base + tslab_b + dp_b + s_b + part_b);
        ctrs     = (unsigned*)(base + tslab_b + dp_b + s_b + part_b + 64);
        unsigned* g_tptr = ctrs;

        hipMemsetAsync(ctrs, 0, 1024 * sizeof(unsigned), stream);
        gather_bin_f32_kernel<<<GB_BLOCKS, 1024, 0, stream>>>(
            pin_pos, flat_netpin, tslab, g_tptr);
        accum_kernel<<<NBUCKET * NSLICE, 256, 0, stream>>>(tslab, g_tptr, Dp);
    }

    scanA_kernel <<<NB, 512, 0, stream>>>(Dp, S);
    scanB_kernel <<<NB, 512, 0, stream>>>(S);
    reduce_kernel<<<RED_BLOCKS, 256, 0, stream>>>(pos, nsx, nsy, S, partials);
    finish_kernel<<<1, 256, 0, stream>>>(partials, sums);
    final_kernel <<<(N_NODES / 4 + 255) / 256, 256, 0, stream>>>(pos, nsx, nsy, S, sums, out);
}